// Round 1
// baseline (1058.099 us; speedup 1.0000x reference)
//
#include <hip/hip_runtime.h>
#include <hip/hip_bf16.h>
#include <math.h>

// MultiSimilarityLoss on MI355X.
// x: [n,128] fp32 L2-normalized; t: [n] int32 labels; out: 4 fp32
// (loss, prec, mean_pos_sim(last row), mean_neg_sim(last row)).
// ep = EPOCH_NUM/300 = 1.0, BASE=0.5, POS_MARGIN=0.9, NEG_MARGIN=0.1.

#define D 128

// ---------------- wave/block reduce helpers ----------------
__device__ inline float waveSum(float v) {
    #pragma unroll
    for (int o = 32; o > 0; o >>= 1) v += __shfl_down(v, o, 64);
    return v;
}
__device__ inline float waveMin(float v) {
    #pragma unroll
    for (int o = 32; o > 0; o >>= 1) v = fminf(v, __shfl_down(v, o, 64));
    return v;
}

// ---------------- kernel 1: per-row positive stats ----------------
// One block per row i: scan all j, same-label pairs with sim<0.9 contribute.
__global__ __launch_bounds__(256) void pos_kernel(
    const float* __restrict__ x, const int* __restrict__ t,
    float* __restrict__ pos_min, float* __restrict__ pos_sum,
    float* __restrict__ last4, int n)
{
    const int i = blockIdx.x;
    const int tid = threadIdx.x;
    __shared__ __align__(16) float xi[D];
    __shared__ float rbuf[4][4];

    if (tid < D / 4) ((float4*)xi)[tid] = ((const float4*)(x + (size_t)i * D))[tid];
    const int ti = t[i];
    __syncthreads();

    float mn = INFINITY, ps = 0.f, ss = 0.f, sc = 0.f;
    for (int j = tid; j < n; j += 256) {
        if (t[j] == ti) {
            const float4* xr = (const float4*)(x + (size_t)j * D);
            const float4* xu = (const float4*)xi;
            float d0 = 0.f, d1 = 0.f, d2 = 0.f, d3 = 0.f;
            #pragma unroll
            for (int q = 0; q < D / 4; ++q) {
                float4 v = xr[q]; float4 u = xu[q];
                d0 += v.x * u.x; d1 += v.y * u.y; d2 += v.z * u.z; d3 += v.w * u.w;
            }
            float d = (d0 + d1) + (d2 + d3);
            if (d < 0.9f) {
                mn = fminf(mn, d);
                float dm = d - 0.9f;
                ps += expf(-2.0f * (d - 0.5f) + dm * dm);   // ep = 1.0
                ss += d; sc += 1.f;
            }
        }
    }
    const int lane = tid & 63, wid = tid >> 6;
    mn = waveMin(mn); ps = waveSum(ps); ss = waveSum(ss); sc = waveSum(sc);
    if (lane == 0) { rbuf[0][wid] = mn; rbuf[1][wid] = ps; rbuf[2][wid] = ss; rbuf[3][wid] = sc; }
    __syncthreads();
    if (tid == 0) {
        float m = fminf(fminf(rbuf[0][0], rbuf[0][1]), fminf(rbuf[0][2], rbuf[0][3]));
        float p = rbuf[1][0] + rbuf[1][1] + rbuf[1][2] + rbuf[1][3];
        float s = rbuf[2][0] + rbuf[2][1] + rbuf[2][2] + rbuf[2][3];
        float c = rbuf[3][0] + rbuf[3][1] + rbuf[3][2] + rbuf[3][3];
        pos_min[i] = m;
        pos_sum[i] = p;
        if (i == n - 1) { last4[0] = s; last4[1] = c; }
    }
}

// ---------------- kernel 2: fused sim GEMM + negative epilogue ----------------
// 128x128 tile per 256-thread block, 8x8 micro-tile, BK=32, k-major LDS.
#define BM 128
#define BN 128
#define BK 32

__global__ __launch_bounds__(256) void neg_kernel(
    const float* __restrict__ x, const int* __restrict__ t,
    const float* __restrict__ pos_min,
    float* __restrict__ neg_sum, float* __restrict__ neg_cnt,
    float* __restrict__ last4, int n)
{
    __shared__ float As[BK][BM];   // 16 KB, k-major
    __shared__ float Bs[BK][BN];   // 16 KB
    __shared__ int   labr[BM], labc[BN];
    __shared__ float pmins[BM];
    __shared__ float redn[BM], redc[BM];

    const int tid = threadIdx.x;
    const int tx = tid & 15, ty = tid >> 4;
    const int i0 = blockIdx.y * BM, j0 = blockIdx.x * BN;

    for (int l = tid; l < BM; l += 256) {
        labr[l] = t[i0 + l];
        labc[l] = t[j0 + l];
        pmins[l] = pos_min[i0 + l];
        redn[l] = 0.f; redc[l] = 0.f;
    }

    float acc[8][8];
    #pragma unroll
    for (int r = 0; r < 8; ++r)
        #pragma unroll
        for (int c = 0; c < 8; ++c) acc[r][c] = 0.f;

    for (int kb = 0; kb < D / BK; ++kb) {
        const int k0 = kb * BK;
        __syncthreads();   // protect LDS (and cover init on first iter)
        // stage A,B tiles transposed: 128 rows x 8 float4 each = 1024 float4
        #pragma unroll
        for (int l = 0; l < 4; ++l) {
            int idx = tid + l * 256;
            int row = idx & 127, kq = idx >> 7;    // kq in 0..7
            float4 va = *(const float4*)(x + (size_t)(i0 + row) * D + k0 + kq * 4);
            As[kq * 4 + 0][row] = va.x; As[kq * 4 + 1][row] = va.y;
            As[kq * 4 + 2][row] = va.z; As[kq * 4 + 3][row] = va.w;
            float4 vb = *(const float4*)(x + (size_t)(j0 + row) * D + k0 + kq * 4);
            Bs[kq * 4 + 0][row] = vb.x; Bs[kq * 4 + 1][row] = vb.y;
            Bs[kq * 4 + 2][row] = vb.z; Bs[kq * 4 + 3][row] = vb.w;
        }
        __syncthreads();
        #pragma unroll 8
        for (int k = 0; k < BK; ++k) {
            float a[8], b[8];
            *(float4*)&a[0] = *(const float4*)&As[k][ty * 8];
            *(float4*)&a[4] = *(const float4*)&As[k][ty * 8 + 4];
            *(float4*)&b[0] = *(const float4*)&Bs[k][tx * 8];
            *(float4*)&b[4] = *(const float4*)&Bs[k][tx * 8 + 4];
            #pragma unroll
            for (int r = 0; r < 8; ++r)
                #pragma unroll
                for (int c = 0; c < 8; ++c)
                    acc[r][c] += a[r] * b[c];
        }
    }
    __syncthreads();

    // epilogue: negative-pair terms
    #pragma unroll
    for (int r = 0; r < 8; ++r) {
        const int row = ty * 8 + r;
        const int gi = i0 + row;
        const float pmin = pmins[row];
        const int lr = labr[row];
        float ns = 0.f, nc = 0.f, ssim = 0.f;
        #pragma unroll
        for (int c = 0; c < 8; ++c) {
            const int col = tx * 8 + c;
            const float s = acc[r][c];
            if (lr != labc[col] && s > 0.1f && s + 0.5f > pmin) {
                float dm = 0.1f - s;
                ns += expf(50.0f * (s - 0.5f) + dm * dm);   // ep = 1.0
                nc += 1.f; ssim += s;
            }
        }
        if (nc > 0.f) {
            atomicAdd(&redn[row], ns);
            atomicAdd(&redc[row], nc);
            if (gi == n - 1) {
                atomicAdd(&last4[2], ssim);
                atomicAdd(&last4[3], nc);
            }
        }
    }
    __syncthreads();
    for (int l = tid; l < BM; l += 256) {
        if (redc[l] > 0.f) {
            atomicAdd(&neg_sum[i0 + l], redn[l]);
            atomicAdd(&neg_cnt[i0 + l], redc[l]);
        }
    }
}

// ---------------- kernel 3: finalize ----------------
__global__ __launch_bounds__(256) void finalize_kernel(
    const float* __restrict__ pos_sum, const float* __restrict__ neg_sum,
    const float* __restrict__ neg_cnt, const float* __restrict__ last4,
    float* __restrict__ out, int n)
{
    const int tid = threadIdx.x;
    __shared__ float rbuf[2][4];
    float lsum = 0.f, nno = 0.f;
    for (int i = tid; i < n; i += 256) {
        float nc = neg_cnt[i];
        if (nc > 0.f)
            lsum += 0.5f * log1pf(pos_sum[i]) + (1.0f / 50.0f) * log1pf(neg_sum[i]);
        else
            nno += 1.f;
    }
    const int lane = tid & 63, wid = tid >> 6;
    lsum = waveSum(lsum); nno = waveSum(nno);
    if (lane == 0) { rbuf[0][wid] = lsum; rbuf[1][wid] = nno; }
    __syncthreads();
    if (tid == 0) {
        float L = rbuf[0][0] + rbuf[0][1] + rbuf[0][2] + rbuf[0][3];
        float P = rbuf[1][0] + rbuf[1][1] + rbuf[1][2] + rbuf[1][3];
        out[0] = L / (float)n;
        out[1] = P / (float)n;
        out[2] = last4[0] / fmaxf(last4[1], 1.f);
        out[3] = last4[2] / fmaxf(last4[3], 1.f);
    }
}

// ---------------- launch ----------------
extern "C" void kernel_launch(void* const* d_in, const int* in_sizes, int n_in,
                              void* d_out, int out_size, void* d_ws, size_t ws_size,
                              hipStream_t stream) {
    const float* x = (const float*)d_in[0];
    const int*   t = (const int*)d_in[1];
    const int n = in_sizes[1];   // 8192

    float* ws      = (float*)d_ws;
    float* pos_min = ws;             // [n]
    float* pos_sum = ws + n;         // [n]
    float* neg_sum = ws + 2 * n;     // [n] zero-init
    float* neg_cnt = ws + 3 * n;     // [n] zero-init
    float* last4   = ws + 4 * n;     // [4]: pos_sim_sum, pos_cnt, neg_sim_sum, neg_cnt

    hipMemsetAsync(neg_sum, 0, (size_t)(2 * n + 4) * sizeof(float), stream);

    pos_kernel<<<n, 256, 0, stream>>>(x, t, pos_min, pos_sum, last4, n);

    dim3 grid(n / BN, n / BM);
    neg_kernel<<<grid, 256, 0, stream>>>(x, t, pos_min, neg_sum, neg_cnt, last4, n);

    finalize_kernel<<<1, 256, 0, stream>>>(pos_sum, neg_sum, neg_cnt, last4,
                                           (float*)d_out, n);
}

// Round 2
// 406.132 us; speedup vs baseline: 2.6053x; 2.6053x over previous
//
#include <hip/hip_runtime.h>
#include <hip/hip_bf16.h>
#include <math.h>

// MultiSimilarityLoss on MI355X.
// x: [n,128] fp32 L2-normalized; t: [n] int32 labels; out: 4 fp32
// (loss, prec, mean_pos_sim(last row), mean_neg_sim(last row)).
// ep = EPOCH_NUM/300 = 1.0, BASE=0.5, POS_MARGIN=0.9, NEG_MARGIN=0.1.

#define D 128
#define NL 128   // labels are 0..99; padded to 128

// ---------------- wave/block reduce helpers ----------------
__device__ inline float waveSum(float v) {
    #pragma unroll
    for (int o = 32; o > 0; o >>= 1) v += __shfl_down(v, o, 64);
    return v;
}
__device__ inline float waveMin(float v) {
    #pragma unroll
    for (int o = 32; o > 0; o >>= 1) v = fminf(v, __shfl_down(v, o, 64));
    return v;
}

// ---------------- kernel 0: bucket indices by label (single block) ----------
__global__ __launch_bounds__(1024) void setup_kernel(
    const int* __restrict__ t, int* __restrict__ offs, int* __restrict__ list,
    int n)
{
    __shared__ int cnt[NL], cur[NL];
    const int tid = threadIdx.x;
    if (tid < NL) cnt[tid] = 0;
    __syncthreads();
    for (int j = tid; j < n; j += 1024) atomicAdd(&cnt[t[j]], 1);
    __syncthreads();
    if (tid == 0) {
        int acc = 0;
        for (int g = 0; g < NL; ++g) { cur[g] = acc; offs[g] = acc; acc += cnt[g]; }
        offs[NL] = acc;
    }
    __syncthreads();
    for (int j = tid; j < n; j += 1024) {
        int p = atomicAdd(&cur[t[j]], 1);
        list[p] = j;
    }
}

// ---------------- kernel 1: per-row positive stats (one wave per row) ------
// Only same-label columns (from the bucket list) are visited: ~82 per row.
__global__ __launch_bounds__(256) void pos_kernel2(
    const float* __restrict__ x, const int* __restrict__ t,
    const int* __restrict__ offs, const int* __restrict__ list,
    float* __restrict__ pos_min, float* __restrict__ pos_sum,
    float* __restrict__ last4, int n)
{
    const int tid = threadIdx.x;
    const int wid = tid >> 6, lane = tid & 63;
    const int i = blockIdx.x * 4 + wid;
    __shared__ __align__(16) float xi[4][D];

    if (tid < 128) {                       // 4 rows x 32 float4
        int r = tid >> 5, q = tid & 31;
        int row = blockIdx.x * 4 + r;
        if (row < n)
            ((float4*)xi[r])[q] = ((const float4*)(x + (size_t)row * D))[q];
    }
    __syncthreads();
    if (i >= n) return;

    const int g = t[i];
    const int s0 = offs[g], s1 = offs[g + 1];
    float mn = INFINITY, ps = 0.f, ss = 0.f, sc = 0.f;
    const float4* xu = (const float4*)xi[wid];
    for (int l = s0 + lane; l < s1; l += 64) {
        const int j = list[l];
        const float4* xr = (const float4*)(x + (size_t)j * D);
        float d0 = 0.f, d1 = 0.f, d2 = 0.f, d3 = 0.f;
        #pragma unroll
        for (int q = 0; q < D / 4; ++q) {
            float4 v = xr[q]; float4 u = xu[q];
            d0 += v.x * u.x; d1 += v.y * u.y; d2 += v.z * u.z; d3 += v.w * u.w;
        }
        float d = (d0 + d1) + (d2 + d3);
        if (d < 0.9f) {                    // excludes j==i (sim ~ 1.0)
            mn = fminf(mn, d);
            float dm = d - 0.9f;
            ps += expf(-2.0f * (d - 0.5f) + dm * dm);   // ep = 1.0
            ss += d; sc += 1.f;
        }
    }
    mn = waveMin(mn); ps = waveSum(ps); ss = waveSum(ss); sc = waveSum(sc);
    if (lane == 0) {
        pos_min[i] = mn;
        pos_sum[i] = ps;
        if (i == n - 1) { last4[0] = ss; last4[1] = sc; }
    }
}

// ---------------- kernel 2: fused sim GEMM + negative epilogue ----------------
// 128x128 tile per 256-thread block, 8x8 micro-tile, BK=32, k-major LDS.
#define BM 128
#define BN 128
#define BK 32

__global__ __launch_bounds__(256) void neg_kernel(
    const float* __restrict__ x, const int* __restrict__ t,
    const float* __restrict__ pos_min,
    float* __restrict__ neg_sum, float* __restrict__ neg_cnt,
    float* __restrict__ last4, int n)
{
    __shared__ float As[BK][BM];   // 16 KB, k-major
    __shared__ float Bs[BK][BN];   // 16 KB
    __shared__ int   labr[BM], labc[BN];
    __shared__ float pmins[BM];
    __shared__ float redn[BM], redc[BM];

    const int tid = threadIdx.x;
    const int tx = tid & 15, ty = tid >> 4;
    const int i0 = blockIdx.y * BM, j0 = blockIdx.x * BN;

    for (int l = tid; l < BM; l += 256) {
        labr[l] = t[i0 + l];
        labc[l] = t[j0 + l];
        pmins[l] = pos_min[i0 + l];
        redn[l] = 0.f; redc[l] = 0.f;
    }

    float acc[8][8];
    #pragma unroll
    for (int r = 0; r < 8; ++r)
        #pragma unroll
        for (int c = 0; c < 8; ++c) acc[r][c] = 0.f;

    for (int kb = 0; kb < D / BK; ++kb) {
        const int k0 = kb * BK;
        __syncthreads();   // protect LDS (and cover init on first iter)
        #pragma unroll
        for (int l = 0; l < 4; ++l) {
            int idx = tid + l * 256;
            int row = idx & 127, kq = idx >> 7;    // kq in 0..7
            float4 va = *(const float4*)(x + (size_t)(i0 + row) * D + k0 + kq * 4);
            As[kq * 4 + 0][row] = va.x; As[kq * 4 + 1][row] = va.y;
            As[kq * 4 + 2][row] = va.z; As[kq * 4 + 3][row] = va.w;
            float4 vb = *(const float4*)(x + (size_t)(j0 + row) * D + k0 + kq * 4);
            Bs[kq * 4 + 0][row] = vb.x; Bs[kq * 4 + 1][row] = vb.y;
            Bs[kq * 4 + 2][row] = vb.z; Bs[kq * 4 + 3][row] = vb.w;
        }
        __syncthreads();
        #pragma unroll 8
        for (int k = 0; k < BK; ++k) {
            float a[8], b[8];
            *(float4*)&a[0] = *(const float4*)&As[k][ty * 8];
            *(float4*)&a[4] = *(const float4*)&As[k][ty * 8 + 4];
            *(float4*)&b[0] = *(const float4*)&Bs[k][tx * 8];
            *(float4*)&b[4] = *(const float4*)&Bs[k][tx * 8 + 4];
            #pragma unroll
            for (int r = 0; r < 8; ++r)
                #pragma unroll
                for (int c = 0; c < 8; ++c)
                    acc[r][c] += a[r] * b[c];
        }
    }
    __syncthreads();

    // epilogue: negative-pair terms
    #pragma unroll
    for (int r = 0; r < 8; ++r) {
        const int row = ty * 8 + r;
        const int gi = i0 + row;
        const float pmin = pmins[row];
        const int lr = labr[row];
        float ns = 0.f, nc = 0.f, ssim = 0.f;
        #pragma unroll
        for (int c = 0; c < 8; ++c) {
            const int col = tx * 8 + c;
            const float s = acc[r][c];
            if (lr != labc[col] && s > 0.1f && s + 0.5f > pmin) {
                float dm = 0.1f - s;
                ns += expf(50.0f * (s - 0.5f) + dm * dm);   // ep = 1.0
                nc += 1.f; ssim += s;
            }
        }
        if (nc > 0.f) {
            atomicAdd(&redn[row], ns);
            atomicAdd(&redc[row], nc);
            if (gi == n - 1) {
                atomicAdd(&last4[2], ssim);
                atomicAdd(&last4[3], nc);
            }
        }
    }
    __syncthreads();
    for (int l = tid; l < BM; l += 256) {
        if (redc[l] > 0.f) {
            atomicAdd(&neg_sum[i0 + l], redn[l]);
            atomicAdd(&neg_cnt[i0 + l], redc[l]);
        }
    }
}

// ---------------- kernel 3: finalize ----------------
__global__ __launch_bounds__(256) void finalize_kernel(
    const float* __restrict__ pos_sum, const float* __restrict__ neg_sum,
    const float* __restrict__ neg_cnt, const float* __restrict__ last4,
    float* __restrict__ out, int n)
{
    const int tid = threadIdx.x;
    __shared__ float rbuf[2][4];
    float lsum = 0.f, nno = 0.f;
    for (int i = tid; i < n; i += 256) {
        float nc = neg_cnt[i];
        if (nc > 0.f)
            lsum += 0.5f * log1pf(pos_sum[i]) + (1.0f / 50.0f) * log1pf(neg_sum[i]);
        else
            nno += 1.f;
    }
    const int lane = tid & 63, wid = tid >> 6;
    lsum = waveSum(lsum); nno = waveSum(nno);
    if (lane == 0) { rbuf[0][wid] = lsum; rbuf[1][wid] = nno; }
    __syncthreads();
    if (tid == 0) {
        float L = rbuf[0][0] + rbuf[0][1] + rbuf[0][2] + rbuf[0][3];
        float P = rbuf[1][0] + rbuf[1][1] + rbuf[1][2] + rbuf[1][3];
        out[0] = L / (float)n;
        out[1] = P / (float)n;
        out[2] = last4[0] / fmaxf(last4[1], 1.f);
        out[3] = last4[2] / fmaxf(last4[3], 1.f);
    }
}

// ---------------- launch ----------------
extern "C" void kernel_launch(void* const* d_in, const int* in_sizes, int n_in,
                              void* d_out, int out_size, void* d_ws, size_t ws_size,
                              hipStream_t stream) {
    const float* x = (const float*)d_in[0];
    const int*   t = (const int*)d_in[1];
    const int n = in_sizes[1];   // 8192

    float* ws      = (float*)d_ws;
    float* pos_min = ws;             // [n]
    float* pos_sum = ws + n;         // [n]
    float* neg_sum = ws + 2 * n;     // [n] zero-init
    float* neg_cnt = ws + 3 * n;     // [n] zero-init
    float* last4   = ws + 4 * n;     // [4]
    int*   offs    = (int*)(ws + 4 * n + 4);      // [NL+1]
    int*   list    = (int*)(ws + 4 * n + 4 + NL + 1);  // [n]

    hipMemsetAsync(neg_sum, 0, (size_t)(2 * n + 4) * sizeof(float), stream);

    setup_kernel<<<1, 1024, 0, stream>>>(t, offs, list, n);

    pos_kernel2<<<(n + 3) / 4, 256, 0, stream>>>(x, t, offs, list,
                                                 pos_min, pos_sum, last4, n);

    dim3 grid(n / BN, n / BM);
    neg_kernel<<<grid, 256, 0, stream>>>(x, t, pos_min, neg_sum, neg_cnt, last4, n);

    finalize_kernel<<<1, 256, 0, stream>>>(pos_sum, neg_sum, neg_cnt, last4,
                                           (float*)d_out, n);
}

// Round 3
// 236.000 us; speedup vs baseline: 4.4835x; 1.7209x over previous
//
#include <hip/hip_runtime.h>
#include <hip/hip_bf16.h>
#include <math.h>

// MultiSimilarityLoss on MI355X.
// x: [n,128] fp32 L2-normalized; t: [n] int32 labels; out: 4 fp32
// (loss, prec, mean_pos_sim(last row), mean_neg_sim(last row)).
// ep = EPOCH_NUM/300 = 1.0, BASE=0.5, POS_MARGIN=0.9, NEG_MARGIN=0.1.
//
// R3: sim GEMM on matrix cores (bf16 MFMA 16x16x32, verified layouts:
// A/B [m=lane&15][k=quad*8+j], C/D col=lane&15 row=quad*4+reg).
// bf16 sim error ~4e-4; (1/50)*log1p cancels the exp(50*) sensitivity.

#define D 128
#define NL 128   // labels are 0..99; padded

typedef __attribute__((ext_vector_type(8))) short short8;
typedef __attribute__((ext_vector_type(4))) float float4v;

// ---------------- wave/block reduce helpers ----------------
__device__ inline float waveSum(float v) {
    #pragma unroll
    for (int o = 32; o > 0; o >>= 1) v += __shfl_down(v, o, 64);
    return v;
}
__device__ inline float waveMin(float v) {
    #pragma unroll
    for (int o = 32; o > 0; o >>= 1) v = fminf(v, __shfl_down(v, o, 64));
    return v;
}

// ---------------- kernel -1: fp32 -> bf16 convert (RNE) ----------------
__global__ __launch_bounds__(256) void convert_kernel(
    const float* __restrict__ x, ushort* __restrict__ xb, int total8)
{
    const int g = blockIdx.x * 256 + threadIdx.x;   // one 8-elem chunk
    if (g >= total8) return;
    const float4* src = (const float4*)(x) + g * 2;
    float4 a = src[0], b = src[1];
    float f[8] = {a.x, a.y, a.z, a.w, b.x, b.y, b.z, b.w};
    ushort r[8];
    #pragma unroll
    for (int i = 0; i < 8; ++i) {
        unsigned u = __float_as_uint(f[i]);
        r[i] = (ushort)((u + 0x7FFFu + ((u >> 16) & 1u)) >> 16);   // RNE
    }
    uint4 packed;
    packed.x = (unsigned)r[0] | ((unsigned)r[1] << 16);
    packed.y = (unsigned)r[2] | ((unsigned)r[3] << 16);
    packed.z = (unsigned)r[4] | ((unsigned)r[5] << 16);
    packed.w = (unsigned)r[6] | ((unsigned)r[7] << 16);
    ((uint4*)xb)[g] = packed;
}

// ---------------- kernel 0: bucket indices by label (single block) ----------
__global__ __launch_bounds__(1024) void setup_kernel(
    const int* __restrict__ t, int* __restrict__ offs, int* __restrict__ list,
    int n)
{
    __shared__ int cnt[NL], cur[NL];
    const int tid = threadIdx.x;
    if (tid < NL) cnt[tid] = 0;
    __syncthreads();
    for (int j = tid; j < n; j += 1024) atomicAdd(&cnt[t[j]], 1);
    __syncthreads();
    if (tid == 0) {
        int acc = 0;
        for (int g = 0; g < NL; ++g) { cur[g] = acc; offs[g] = acc; acc += cnt[g]; }
        offs[NL] = acc;
    }
    __syncthreads();
    for (int j = tid; j < n; j += 1024) {
        int p = atomicAdd(&cur[t[j]], 1);
        list[p] = j;
    }
}

// ---------------- kernel 1: per-row positive stats (one wave per row) ------
// Columns gathered from bf16 copy (halves gather bytes); own row stays fp32.
__global__ __launch_bounds__(256) void pos_kernel2(
    const float* __restrict__ x, const ushort* __restrict__ xb,
    const int* __restrict__ t,
    const int* __restrict__ offs, const int* __restrict__ list,
    float* __restrict__ pos_min, float* __restrict__ pos_sum,
    float* __restrict__ last4, int n)
{
    const int tid = threadIdx.x;
    const int wid = tid >> 6, lane = tid & 63;
    const int i = blockIdx.x * 4 + wid;
    __shared__ __align__(16) float xi[4][D];

    if (tid < 128) {                       // 4 rows x 32 float4
        int r = tid >> 5, q = tid & 31;
        int row = blockIdx.x * 4 + r;
        if (row < n)
            ((float4*)xi[r])[q] = ((const float4*)(x + (size_t)row * D))[q];
    }
    __syncthreads();
    if (i >= n) return;

    const int g = t[i];
    const int s0 = offs[g], s1 = offs[g + 1];
    float mn = INFINITY, ps = 0.f, ss = 0.f, sc = 0.f;
    const float* xu = xi[wid];
    for (int l = s0 + lane; l < s1; l += 64) {
        const int j = list[l];
        const uint4* xr = (const uint4*)(xb + (size_t)j * D);
        float d = 0.f;
        #pragma unroll
        for (int q = 0; q < 16; ++q) {
            uint4 v = xr[q];
            const float* u = xu + q * 8;
            d += __uint_as_float(v.x << 16)          * u[0];
            d += __uint_as_float(v.x & 0xffff0000u)  * u[1];
            d += __uint_as_float(v.y << 16)          * u[2];
            d += __uint_as_float(v.y & 0xffff0000u)  * u[3];
            d += __uint_as_float(v.z << 16)          * u[4];
            d += __uint_as_float(v.z & 0xffff0000u)  * u[5];
            d += __uint_as_float(v.w << 16)          * u[6];
            d += __uint_as_float(v.w & 0xffff0000u)  * u[7];
        }
        if (d < 0.9f) {                    // excludes j==i (sim ~ 1.0)
            mn = fminf(mn, d);
            float dm = d - 0.9f;
            ps += expf(-2.0f * (d - 0.5f) + dm * dm);   // ep = 1.0
            ss += d; sc += 1.f;
        }
    }
    mn = waveMin(mn); ps = waveSum(ps); ss = waveSum(ss); sc = waveSum(sc);
    if (lane == 0) {
        pos_min[i] = mn;
        pos_sum[i] = ps;
        if (i == n - 1) { last4[0] = ss; last4[1] = sc; }
    }
}

// ---------------- kernel 2: MFMA sim GEMM + negative epilogue ----------------
// 128x128 tile per 256-thread block (4 waves, each 64x64 via 4x4 MFMA tiles).
// Whole K=128 staged once into LDS; 16B chunks XOR-swizzled by row&15.
__global__ __launch_bounds__(256) void neg_kernel_mfma(
    const ushort* __restrict__ xb, const int* __restrict__ t,
    const float* __restrict__ pos_min,
    float* __restrict__ neg_sum, float* __restrict__ neg_cnt,
    float* __restrict__ last4, int n)
{
    __shared__ __align__(16) ushort A_lds[128 * 128];   // 32 KB
    __shared__ __align__(16) ushort B_lds[128 * 128];   // 32 KB
    __shared__ int   labr[128], labc[128];
    __shared__ float pmins[128];
    __shared__ float redn[128], redc[128];

    const int tid = threadIdx.x;
    const int w = tid >> 6, lane = tid & 63;
    const int wy = w >> 1, wx = w & 1;
    const int quad = lane >> 4, lq = lane & 15;
    const int i0 = blockIdx.y * 128, j0 = blockIdx.x * 128;

    for (int l = tid; l < 128; l += 256) {
        labr[l] = t[i0 + l];
        labc[l] = t[j0 + l];
        pmins[l] = pos_min[i0 + l];
        redn[l] = 0.f; redc[l] = 0.f;
    }

    // stage A,B tiles (bf16, 16B chunks, swizzled: chunk c -> c ^ (row&15))
    {
        const uint4* xbv = (const uint4*)xb;
        uint4* Au = (uint4*)A_lds;
        uint4* Bu = (uint4*)B_lds;
        #pragma unroll
        for (int it = 0; it < 8; ++it) {
            int g = tid + it * 256;
            int row = g >> 4, c = g & 15;
            int cs = c ^ (row & 15);
            Au[row * 16 + cs] = xbv[(size_t)(i0 + row) * 16 + c];
            Bu[row * 16 + cs] = xbv[(size_t)(j0 + row) * 16 + c];
        }
    }
    __syncthreads();

    float4v acc[4][4];
    #pragma unroll
    for (int r = 0; r < 4; ++r)
        #pragma unroll
        for (int c = 0; c < 4; ++c) acc[r][c] = (float4v){0.f, 0.f, 0.f, 0.f};

    const short8* As = (const short8*)A_lds;
    const short8* Bs = (const short8*)B_lds;
    #pragma unroll
    for (int s = 0; s < 4; ++s) {           // K-step: k = s*32 + quad*8 + j
        const int swz = (s * 4 + quad) ^ lq;  // chunk index ^ (row&15), row&15==lq
        short8 a[4], b[4];
        #pragma unroll
        for (int tt = 0; tt < 4; ++tt) {
            a[tt] = As[(wy * 64 + tt * 16 + lq) * 16 + swz];
            b[tt] = Bs[(wx * 64 + tt * 16 + lq) * 16 + swz];
        }
        #pragma unroll
        for (int tr = 0; tr < 4; ++tr)
            #pragma unroll
            for (int tc = 0; tc < 4; ++tc)
                acc[tr][tc] = __builtin_amdgcn_mfma_f32_16x16x32_bf16(
                    a[tr], b[tc], acc[tr][tc], 0, 0, 0);
    }

    // epilogue: negative-pair terms; row = quad*4+reg, col = lane&15 (per tile)
    #pragma unroll
    for (int tr = 0; tr < 4; ++tr) {
        #pragma unroll
        for (int reg = 0; reg < 4; ++reg) {
            const int row_loc = wy * 64 + tr * 16 + quad * 4 + reg;
            const int gi = i0 + row_loc;
            const float pmin = pmins[row_loc];
            const int lr = labr[row_loc];
            float ns = 0.f, nc = 0.f, ssim = 0.f;
            #pragma unroll
            for (int tc = 0; tc < 4; ++tc) {
                const int col_loc = wx * 64 + tc * 16 + lq;
                const float s = acc[tr][tc][reg];
                if (lr != labc[col_loc] && s > 0.1f && s + 0.5f > pmin) {
                    float dm = 0.1f - s;
                    ns += expf(50.0f * (s - 0.5f) + dm * dm);   // ep = 1.0
                    nc += 1.f; ssim += s;
                }
            }
            // reduce across the 16-lane subgroup (same quad => same row)
            #pragma unroll
            for (int o = 1; o < 16; o <<= 1) {
                ns   += __shfl_xor(ns, o, 64);
                nc   += __shfl_xor(nc, o, 64);
                ssim += __shfl_xor(ssim, o, 64);
            }
            if (lq == 0 && nc > 0.f) {
                atomicAdd(&redn[row_loc], ns);
                atomicAdd(&redc[row_loc], nc);
                if (gi == n - 1) {
                    atomicAdd(&last4[2], ssim);
                    atomicAdd(&last4[3], nc);
                }
            }
        }
    }
    __syncthreads();
    for (int l = tid; l < 128; l += 256) {
        if (redc[l] > 0.f) {
            atomicAdd(&neg_sum[i0 + l], redn[l]);
            atomicAdd(&neg_cnt[i0 + l], redc[l]);
        }
    }
}

// ---------------- kernel 3: finalize ----------------
__global__ __launch_bounds__(256) void finalize_kernel(
    const float* __restrict__ pos_sum, const float* __restrict__ neg_sum,
    const float* __restrict__ neg_cnt, const float* __restrict__ last4,
    float* __restrict__ out, int n)
{
    const int tid = threadIdx.x;
    __shared__ float rbuf[2][4];
    float lsum = 0.f, nno = 0.f;
    for (int i = tid; i < n; i += 256) {
        float nc = neg_cnt[i];
        if (nc > 0.f)
            lsum += 0.5f * log1pf(pos_sum[i]) + (1.0f / 50.0f) * log1pf(neg_sum[i]);
        else
            nno += 1.f;
    }
    const int lane = tid & 63, wid = tid >> 6;
    lsum = waveSum(lsum); nno = waveSum(nno);
    if (lane == 0) { rbuf[0][wid] = lsum; rbuf[1][wid] = nno; }
    __syncthreads();
    if (tid == 0) {
        float L = rbuf[0][0] + rbuf[0][1] + rbuf[0][2] + rbuf[0][3];
        float P = rbuf[1][0] + rbuf[1][1] + rbuf[1][2] + rbuf[1][3];
        out[0] = L / (float)n;
        out[1] = P / (float)n;
        out[2] = last4[0] / fmaxf(last4[1], 1.f);
        out[3] = last4[2] / fmaxf(last4[3], 1.f);
    }
}

// ---------------- launch ----------------
extern "C" void kernel_launch(void* const* d_in, const int* in_sizes, int n_in,
                              void* d_out, int out_size, void* d_ws, size_t ws_size,
                              hipStream_t stream) {
    const float* x = (const float*)d_in[0];
    const int*   t = (const int*)d_in[1];
    const int n = in_sizes[1];   // 8192

    float* ws      = (float*)d_ws;
    float* pos_min = ws;                      // [n]
    float* pos_sum = ws + n;                  // [n]
    float* neg_sum = ws + 2 * n;              // [n] zero-init
    float* neg_cnt = ws + 3 * n;              // [n] zero-init
    float* last4   = ws + 4 * n;              // [4]  zero-init
    int*   offs    = (int*)(ws + 4 * n + 4);          // [NL+1]
    int*   list    = (int*)(ws + 4 * n + 4 + NL + 1); // [n]
    // bf16 copy of x, 16B-aligned: floats offset 5n+133 rounded up to mult of 4
    size_t xb_off = (size_t)(5 * n + 133 + 3) & ~(size_t)3;
    ushort* xb = (ushort*)(ws + xb_off);              // [n*128] bf16

    hipMemsetAsync(neg_sum, 0, (size_t)(2 * n + 4) * sizeof(float), stream);

    const int total8 = n * D / 8;
    convert_kernel<<<(total8 + 255) / 256, 256, 0, stream>>>(x, xb, total8);

    setup_kernel<<<1, 1024, 0, stream>>>(t, offs, list, n);

    pos_kernel2<<<(n + 3) / 4, 256, 0, stream>>>(x, xb, t, offs, list,
                                                 pos_min, pos_sum, last4, n);

    dim3 grid(n / 128, n / 128);
    neg_kernel_mfma<<<grid, 256, 0, stream>>>(xb, t, pos_min,
                                              neg_sum, neg_cnt, last4, n);

    finalize_kernel<<<1, 256, 0, stream>>>(pos_sum, neg_sum, neg_cnt, last4,
                                           (float*)d_out, n);
}